// Round 4
// baseline (293.190 us; speedup 1.0000x reference)
//
#include <hip/hip_runtime.h>
#include <hip/hip_bf16.h>

typedef __bf16 bf16x8 __attribute__((ext_vector_type(8)));
typedef __bf16 bf16x4 __attribute__((ext_vector_type(4)));
typedef float f32x4 __attribute__((ext_vector_type(4)));

__device__ __forceinline__ unsigned short f2b(float f) {
    union { float f; unsigned int u; } v; v.f = f;
    unsigned int r = (v.u + 0x7FFFu + ((v.u >> 16) & 1u)) >> 16;
    return (unsigned short)r;
}

__device__ __forceinline__ unsigned int cvtpk(float lo, float hi) {
    unsigned int r;
    asm("v_cvt_pk_bf16_f32 %0, %1, %2" : "=v"(r) : "v"(lo), "v"(hi));
    return r;
}

__device__ __forceinline__ void gload_lds16(const void* g, void* l) {
    __builtin_amdgcn_global_load_lds((__attribute__((address_space(1))) void*)g,
                                     (__attribute__((address_space(3))) void*)l,
                                     16, 0, 0);
}

// ---------------- converts ----------------

__global__ __launch_bounds__(256) void cvt_x_kernel(const float* __restrict__ in,
                                                    unsigned short* __restrict__ out) {
    int i = (blockIdx.x * 256 + threadIdx.x) * 4;
    float4 f = *(const float4*)(in + i);
    ushort4 u;
    u.x = f2b(f.x); u.y = f2b(f.y); u.z = f2b(f.z); u.w = f2b(f.w);
    *(ushort4*)(out + i) = u;
}

// in: R x C fp32, out: C x R bf16 (transposed)
__global__ __launch_bounds__(256) void transpose_cvt(const float* __restrict__ in,
                                                     unsigned short* __restrict__ out,
                                                     int R, int C) {
    __shared__ float t[32][33];
    int c0 = blockIdx.x * 32, r0 = blockIdx.y * 32;
    int tx = threadIdx.x, ty = threadIdx.y;
#pragma unroll
    for (int i = 0; i < 4; i++)
        t[ty + i * 8][tx] = in[(size_t)(r0 + ty + i * 8) * C + c0 + tx];
    __syncthreads();
#pragma unroll
    for (int i = 0; i < 4; i++)
        out[(size_t)(c0 + ty + i * 8) * R + r0 + tx] = f2b(t[tx][ty + i * 8]);
}

// V [bh][n][64] bf16 -> Vt [bh][64][n] bf16   (n tiles of 64)
__global__ __launch_bounds__(256) void vtrans_kernel(const unsigned short* __restrict__ V,
                                                     unsigned short* __restrict__ Vt) {
    __shared__ unsigned short t[64][72];
    int bh = blockIdx.y, n0 = blockIdx.x * 64;
    int r = threadIdx.x >> 2, cg = (threadIdx.x & 3) * 16;
    const unsigned short* src = V + ((size_t)bh * 2048 + n0 + r) * 64 + cg;
    *(bf16x8*)&t[r][cg]     = *(const bf16x8*)src;
    *(bf16x8*)&t[r][cg + 8] = *(const bf16x8*)(src + 8);
    __syncthreads();
    unsigned short tmp[16];
#pragma unroll
    for (int m = 0; m < 16; m++) tmp[m] = t[cg + m][r];
    unsigned short* dst = Vt + ((size_t)bh * 64 + r) * 2048 + n0 + cg;
    *(bf16x8*)dst       = *(const bf16x8*)tmp;
    *(bf16x8*)(dst + 8) = *(const bf16x8*)(tmp + 8);
}

// ---------------- gates: sigmoid(x @ w_gates) -> [b*16+h][n] ----------------

__global__ __launch_bounds__(256) void gates_kernel(const float* __restrict__ x,
                                                    const float* __restrict__ wg,
                                                    float* __restrict__ gates) {
    int row = blockIdx.x;            // 0..4095  (b*2048+n)
    int b = row >> 11, n = row & 2047;
    int t = threadIdx.x;
    int h = t & 15, fi = t >> 4;     // fi 0..15
    const float* xr = x + (size_t)row * 1024;
    float s = 0.f;
    for (int f = fi; f < 1024; f += 16)
        s += xr[f] * wg[f * 16 + h];
    __shared__ float red[16][17];
    red[fi][h] = s;
    __syncthreads();
    if (t < 16) {
        float tot = 0.f;
#pragma unroll
        for (int i = 0; i < 16; i++) tot += red[i][t];
        float g = 1.f / (1.f + __expf(-tot));
        gates[((size_t)(b * 16 + t)) * 2048 + n] = g;
    }
}

// ---------------- GEMM: C = A[M][K] * Bt[N][K]^T, bf16 in, fp32 acc ----------------

template <int EPI>
__global__ __launch_bounds__(256, 2)
void gemm_bt_kernel(const unsigned short* __restrict__ A,
                    const unsigned short* __restrict__ Bt,
                    int M, int N, int K,
                    unsigned short* __restrict__ outQ,
                    unsigned short* __restrict__ outK,
                    unsigned short* __restrict__ outV,
                    float* __restrict__ outF) {
    __shared__ unsigned short As[128 * 32];
    __shared__ unsigned short Bs[128 * 32];
    const int lane = threadIdx.x & 63;
    const int w = threadIdx.x >> 6;
    const int wr = w >> 1, wc = w & 1;
    const int tm = blockIdx.y * 128;
    const int tn = blockIdx.x * 128;

    f32x4 acc[4][4];
#pragma unroll
    for (int m = 0; m < 4; m++)
#pragma unroll
        for (int n = 0; n < 4; n++) acc[m][n] = (f32x4){0.f, 0.f, 0.f, 0.f};

    const int sRow = lane >> 2;
    const int sCol = (lane & 3) * 8;

    const unsigned short* aFragBase = As + (wr * 64 + (lane & 15)) * 32 + (lane >> 4) * 8;
    const unsigned short* bFragBase = Bs + (wc * 64 + (lane & 15)) * 32 + (lane >> 4) * 8;

    for (int k0 = 0; k0 < K; k0 += 32) {
#pragma unroll
        for (int i = 0; i < 2; i++) {
            int chunk = w * 2 + i;
            int r = chunk * 16 + sRow;
            gload_lds16(A + (size_t)(tm + r) * K + k0 + sCol, (void*)(As + chunk * 512));
            gload_lds16(Bt + (size_t)(tn + r) * K + k0 + sCol, (void*)(Bs + chunk * 512));
        }
        __syncthreads();
        bf16x8 af[4], bg[4];
#pragma unroll
        for (int m = 0; m < 4; m++) af[m] = *(const bf16x8*)(aFragBase + m * 16 * 32);
#pragma unroll
        for (int n = 0; n < 4; n++) bg[n] = *(const bf16x8*)(bFragBase + n * 16 * 32);
#pragma unroll
        for (int m = 0; m < 4; m++)
#pragma unroll
            for (int n = 0; n < 4; n++)
                acc[m][n] = __builtin_amdgcn_mfma_f32_16x16x32_bf16(af[m], bg[n], acc[m][n], 0, 0, 0);
        __syncthreads();
    }

#pragma unroll
    for (int m = 0; m < 4; m++) {
        int row = tm + wr * 64 + m * 16 + (lane >> 4) * 4;
#pragma unroll
        for (int n = 0; n < 4; n++) {
            int col = tn + wc * 64 + n * 16 + (lane & 15);
#pragma unroll
            for (int r = 0; r < 4; r++) {
                float val = acc[m][n][r];
                int rr = row + r;
                if (EPI == 0) {
                    int which = col >> 10;
                    int h = (col >> 6) & 15;
                    int d = col & 63;
                    int b = rr >> 11;
                    int nn = rr & 2047;
                    size_t off = (((size_t)(b * 16 + h)) * 2048 + nn) * 64 + d;
                    if (which == 0)      outQ[off] = f2b(val * 0.125f);
                    else if (which == 1) outK[off] = f2b(val);
                    else                 outV[off] = f2b(val);
                } else {
                    outF[(size_t)rr * N + col] = val;
                }
            }
        }
    }
}

// ---------------- flash attention: softcap + causal + gate ----------------
// Swapped-operand structure: S^T = mfma(K, Q) so each lane owns ONE q-row
// (q = lane&15; 64 k-values as 16 regs x 4 lane-groups). Softmax reduce =
// local tree + 2 shfl_xor. P stays in registers (cvt_pk -> PV B-operand).
// O computed transposed: O^T = V^T P^T. No LDS, no barriers.
// 512 blocks = 32 bh x 16 pairs; block does q-tiles {pair, 31-pair} = 33 iters.

__global__ __launch_bounds__(256)
void attn_kernel(const unsigned short* __restrict__ Q,
                 const unsigned short* __restrict__ Kg,
                 const unsigned short* __restrict__ Vt,
                 const float* __restrict__ Gates,
                 unsigned short* __restrict__ Out) {
    const int lane = threadIdx.x & 63;
    const int w = threadIdx.x >> 6;
    const int g = lane >> 4;        // lane-group 0..3
    const int ql = lane & 15;       // q (and d) sub-index

    // XCD-chunked bijective swizzle: XCD i gets blocks [64i, 64i+64) = 4 heads
    const int wgid = (blockIdx.x & 7) * 64 + (blockIdx.x >> 3);
    const int bh = wgid >> 4;
    const int pair = wgid & 15;
    const int b = bh >> 4;
    const int h = bh & 15;

    const size_t headBase = (size_t)bh * 2048 * 64;
    const float LOG2E = 1.4426950408889634f;

    // K fragment base (A-operand): row k=ql, d-slots 8g..8g+7
    const unsigned short* Kfr = Kg + headBase + (size_t)ql * 64 + g * 8;
    // V^T fragment base (A-operand of PV): d-row ql (+n*16), kv chunk start 4g
    const unsigned short* Vfr = Vt + (size_t)bh * 131072 + (size_t)ql * 2048 + g * 4;

    for (int half = 0; half < 2; half++) {
        const int qt = half ? (31 - pair) : pair;
        const int qglob = qt * 64 + w * 16 + ql;

        const unsigned short* qp = Q + headBase + (size_t)qglob * 64 + g * 8;
        bf16x8 qa0 = *(const bf16x8*)qp;
        bf16x8 qa1 = *(const bf16x8*)(qp + 32);

        float mrun = -1e30f, lrun = 0.f;
        f32x4 o[4];
#pragma unroll
        for (int n = 0; n < 4; n++) o[n] = (f32x4){0.f, 0.f, 0.f, 0.f};

        bf16x8 kb[4][2];
#pragma unroll
        for (int n = 0; n < 4; n++) {
            const unsigned short* kp = Kfr + (size_t)(n * 16) * 64;
            kb[n][0] = *(const bf16x8*)kp;
            kb[n][1] = *(const bf16x8*)(kp + 32);
        }

        for (int jt = 0; jt <= qt; ++jt) {
            // S^T = K Q^T : lane holds S[k = jt*64+16n+4g+r][q = qglob]
            f32x4 s[4];
#pragma unroll
            for (int n = 0; n < 4; n++) {
                f32x4 sv = (f32x4){0.f, 0.f, 0.f, 0.f};
                sv = __builtin_amdgcn_mfma_f32_16x16x32_bf16(kb[n][0], qa0, sv, 0, 0, 0);
                sv = __builtin_amdgcn_mfma_f32_16x16x32_bf16(kb[n][1], qa1, sv, 0, 0, 0);
                s[n] = sv;
            }

            // prefetch next K tile (latency hides under softmax)
            {
                int jn = (jt < qt) ? jt + 1 : 0;
#pragma unroll
                for (int n = 0; n < 4; n++) {
                    const unsigned short* kp = Kfr + (size_t)(jn * 64 + n * 16) * 64;
                    kb[n][0] = *(const bf16x8*)kp;
                    kb[n][1] = *(const bf16x8*)(kp + 32);
                }
            }

            // V^T loads for this tile, permuted k-slots: slot 8g+j -> k=16(j>>2)+4g+(j&3)
            bf16x4 va[4][2][2];
            {
                const unsigned short* vbase = Vfr + jt * 64;
#pragma unroll
                for (int n = 0; n < 4; n++) {
                    const unsigned short* vp = vbase + (size_t)(n * 16) * 2048;
                    va[n][0][0] = *(const bf16x4*)(vp);
                    va[n][0][1] = *(const bf16x4*)(vp + 16);
                    va[n][1][0] = *(const bf16x4*)(vp + 32);
                    va[n][1][1] = *(const bf16x4*)(vp + 48);
                }
            }

            // softcap then causal mask (k > q)
            const bool diag = (jt == qt);
#pragma unroll
            for (int n = 0; n < 4; n++) {
                int k0 = jt * 64 + n * 16 + 4 * g;
#pragma unroll
                for (int r = 0; r < 4; r++) {
                    float x = s[n][r];
                    float t = __builtin_amdgcn_exp2f(x * 0.057707801635559964f);
                    float sc = 50.f - 100.f * __builtin_amdgcn_rcpf(t + 1.f);
                    if (diag && (k0 + r) > qglob) sc = -1e30f;
                    s[n][r] = sc;
                }
            }

            // per-lane row reduce: local tree + xor16 + xor32
            float ml = fmaxf(fmaxf(fmaxf(s[0][0], s[0][1]), fmaxf(s[0][2], s[0][3])),
                             fmaxf(fmaxf(s[1][0], s[1][1]), fmaxf(s[1][2], s[1][3])));
            ml = fmaxf(ml, fmaxf(fmaxf(fmaxf(s[2][0], s[2][1]), fmaxf(s[2][2], s[2][3])),
                                 fmaxf(fmaxf(s[3][0], s[3][1]), fmaxf(s[3][2], s[3][3]))));
            ml = fmaxf(ml, __shfl_xor(ml, 16));
            ml = fmaxf(ml, __shfl_xor(ml, 32));

            float mnew = fmaxf(mrun, ml * LOG2E);
            float alpha = __builtin_amdgcn_exp2f(mrun - mnew);
            mrun = mnew;

            float rs = 0.f;
#pragma unroll
            for (int n = 0; n < 4; n++)
#pragma unroll
                for (int r = 0; r < 4; r++) {
                    float p = __builtin_amdgcn_exp2f(__builtin_fmaf(s[n][r], LOG2E, -mrun));
                    s[n][r] = p;
                    rs += p;
                }
            rs += __shfl_xor(rs, 16);
            rs += __shfl_xor(rs, 32);
            lrun = lrun * alpha + rs;

#pragma unroll
            for (int n = 0; n < 4; n++)
#pragma unroll
                for (int r = 0; r < 4; r++) o[n][r] *= alpha;

            // P -> bf16 B-operands entirely in registers
            union PU { unsigned int u[4]; bf16x8 v; };
            PU p0, p1;
            p0.u[0] = cvtpk(s[0][0], s[0][1]);
            p0.u[1] = cvtpk(s[0][2], s[0][3]);
            p0.u[2] = cvtpk(s[1][0], s[1][1]);
            p0.u[3] = cvtpk(s[1][2], s[1][3]);
            p1.u[0] = cvtpk(s[2][0], s[2][1]);
            p1.u[1] = cvtpk(s[2][2], s[2][3]);
            p1.u[2] = cvtpk(s[3][0], s[3][1]);
            p1.u[3] = cvtpk(s[3][2], s[3][3]);

            // O^T += V^T P^T  (same slot->k permutation on both operands)
#pragma unroll
            for (int n = 0; n < 4; n++) {
                bf16x8 va0 = __builtin_shufflevector(va[n][0][0], va[n][0][1], 0, 1, 2, 3, 4, 5, 6, 7);
                bf16x8 va1 = __builtin_shufflevector(va[n][1][0], va[n][1][1], 0, 1, 2, 3, 4, 5, 6, 7);
                o[n] = __builtin_amdgcn_mfma_f32_16x16x32_bf16(va0, p0.v, o[n], 0, 0, 0);
                o[n] = __builtin_amdgcn_mfma_f32_16x16x32_bf16(va1, p1.v, o[n], 0, 0, 0);
            }
        }

        // epilogue: O^T lane: q = qglob, d = n*16 + 4g + r. /l, *gate, pack 4 d.
        float gate = Gates[(size_t)bh * 2048 + qglob];
        float inv = gate / lrun;
        unsigned short* orow = Out + ((size_t)(b * 2048) + qglob) * 1024 + h * 64;
#pragma unroll
        for (int n = 0; n < 4; n++) {
            ushort4 st;
            st.x = f2b(o[n][0] * inv);
            st.y = f2b(o[n][1] * inv);
            st.z = f2b(o[n][2] * inv);
            st.w = f2b(o[n][3] * inv);
            *(ushort4*)(orow + n * 16 + 4 * g) = st;
        }
    }
}

// ---------------- launch ----------------

extern "C" void kernel_launch(void* const* d_in, const int* in_sizes, int n_in,
                              void* d_out, int out_size, void* d_ws, size_t ws_size,
                              hipStream_t stream) {
    const float* x       = (const float*)d_in[0];   // [2][2048][1024]
    const float* w_qkv   = (const float*)d_in[1];   // [1024][3072]
    const float* w_gates = (const float*)d_in[2];   // [1024][16]
    const float* w_out   = (const float*)d_in[3];   // [1024][1024]
    float* out = (float*)d_out;                     // [2][2048][1024]

    char* ws = (char*)d_ws;
    unsigned short* x_bf  = (unsigned short*)(ws);                      // 8 MB (reused as Vt later)
    unsigned short* wqkvT = (unsigned short*)(ws + ((size_t)8  << 20)); // 6 MB
    unsigned short* woutT = (unsigned short*)(ws + ((size_t)14 << 20)); // 2 MB
    unsigned short* qB    = (unsigned short*)(ws + ((size_t)16 << 20)); // 8 MB
    unsigned short* kB    = (unsigned short*)(ws + ((size_t)24 << 20)); // 8 MB
    unsigned short* vB    = (unsigned short*)(ws + ((size_t)32 << 20)); // 8 MB
    float*          gates = (float*)(ws + ((size_t)40 << 20));          // 256 KB
    unsigned short* attnO = (unsigned short*)(ws + ((size_t)41 << 20)); // 8 MB
    unsigned short* vT    = x_bf;                                       // reuse after gemm0

    cvt_x_kernel<<<dim3(4096), dim3(256), 0, stream>>>(x, x_bf);
    transpose_cvt<<<dim3(3072 / 32, 1024 / 32), dim3(32, 8), 0, stream>>>(w_qkv, wqkvT, 1024, 3072);
    transpose_cvt<<<dim3(1024 / 32, 1024 / 32), dim3(32, 8), 0, stream>>>(w_out, woutT, 1024, 1024);
    gates_kernel<<<dim3(4096), dim3(256), 0, stream>>>(x, w_gates, gates);

    gemm_bt_kernel<0><<<dim3(3072 / 128, 4096 / 128), dim3(256), 0, stream>>>(
        x_bf, wqkvT, 4096, 3072, 1024, qB, kB, vB, (float*)nullptr);

    vtrans_kernel<<<dim3(32, 32), dim3(256), 0, stream>>>(vB, vT);

    attn_kernel<<<dim3(512), dim3(256), 0, stream>>>(qB, kB, vT, gates, attnO);

    gemm_bt_kernel<1><<<dim3(1024 / 128, 4096 / 128), dim3(256), 0, stream>>>(
        attnO, woutT, 4096, 1024, 1024, nullptr, nullptr, nullptr, out);
}

// Round 5
// 235.467 us; speedup vs baseline: 1.2451x; 1.2451x over previous
//
#include <hip/hip_runtime.h>
#include <hip/hip_bf16.h>

typedef __bf16 bf16x8 __attribute__((ext_vector_type(8)));
typedef float f32x4 __attribute__((ext_vector_type(4)));

__device__ __forceinline__ unsigned short f2b(float f) {
    union { float f; unsigned int u; } v; v.f = f;
    unsigned int r = (v.u + 0x7FFFu + ((v.u >> 16) & 1u)) >> 16;
    return (unsigned short)r;
}

__device__ __forceinline__ unsigned int cvtpk(float lo, float hi) {
    unsigned int r;
    asm("v_cvt_pk_bf16_f32 %0, %1, %2" : "=v"(r) : "v"(lo), "v"(hi));
    return r;
}

__device__ __forceinline__ void gload_lds16(const void* g, void* l) {
    __builtin_amdgcn_global_load_lds((__attribute__((address_space(1))) void*)g,
                                     (__attribute__((address_space(3))) void*)l,
                                     16, 0, 0);
}

// ---------------- converts ----------------

__global__ __launch_bounds__(256) void cvt_x_kernel(const float* __restrict__ in,
                                                    unsigned short* __restrict__ out) {
    int i = (blockIdx.x * 256 + threadIdx.x) * 4;
    float4 f = *(const float4*)(in + i);
    ushort4 u;
    u.x = f2b(f.x); u.y = f2b(f.y); u.z = f2b(f.z); u.w = f2b(f.w);
    *(ushort4*)(out + i) = u;
}

// in: R x C fp32, out: C x R bf16 (transposed)
__global__ __launch_bounds__(256) void transpose_cvt(const float* __restrict__ in,
                                                     unsigned short* __restrict__ out,
                                                     int R, int C) {
    __shared__ float t[32][33];
    int c0 = blockIdx.x * 32, r0 = blockIdx.y * 32;
    int tx = threadIdx.x, ty = threadIdx.y;
#pragma unroll
    for (int i = 0; i < 4; i++)
        t[ty + i * 8][tx] = in[(size_t)(r0 + ty + i * 8) * C + c0 + tx];
    __syncthreads();
#pragma unroll
    for (int i = 0; i < 4; i++)
        out[(size_t)(c0 + ty + i * 8) * R + r0 + tx] = f2b(t[tx][ty + i * 8]);
}

// V [bh][n][64] bf16 -> Vp [bh][64][n'] bf16, where within each 64-col tile
// the k columns are PERMUTED to match the attn kernel's in-register P layout:
// src col c = 16n + 4g + r  ->  dst col g*16 + n*4 + r
__global__ __launch_bounds__(256) void vtrans_kernel(const unsigned short* __restrict__ V,
                                                     unsigned short* __restrict__ Vp) {
    __shared__ unsigned short t[64][72];
    int bh = blockIdx.y, n0 = blockIdx.x * 64;
    int r = threadIdx.x >> 2, gd = threadIdx.x & 3;
    const unsigned short* src = V + ((size_t)bh * 2048 + n0 + r) * 64 + gd * 16;
    *(bf16x8*)&t[r][gd * 16]     = *(const bf16x8*)src;
    *(bf16x8*)&t[r][gd * 16 + 8] = *(const bf16x8*)(src + 8);
    __syncthreads();
    unsigned short tmp[16];
#pragma unroll
    for (int m = 0; m < 16; m++)
        tmp[m] = t[16 * (m >> 2) + 4 * gd + (m & 3)][r];   // inv-perm gather
    unsigned short* dst = Vp + ((size_t)bh * 64 + r) * 2048 + n0 + gd * 16;
    *(bf16x8*)dst       = *(const bf16x8*)tmp;
    *(bf16x8*)(dst + 8) = *(const bf16x8*)(tmp + 8);
}

// ---------------- gates: sigmoid(x @ w_gates) -> [b*16+h][n] ----------------

__global__ __launch_bounds__(256) void gates_kernel(const float* __restrict__ x,
                                                    const float* __restrict__ wg,
                                                    float* __restrict__ gates) {
    int row = blockIdx.x;            // 0..4095  (b*2048+n)
    int b = row >> 11, n = row & 2047;
    int t = threadIdx.x;
    int h = t & 15, fi = t >> 4;     // fi 0..15
    const float* xr = x + (size_t)row * 1024;
    float s = 0.f;
    for (int f = fi; f < 1024; f += 16)
        s += xr[f] * wg[f * 16 + h];
    __shared__ float red[16][17];
    red[fi][h] = s;
    __syncthreads();
    if (t < 16) {
        float tot = 0.f;
#pragma unroll
        for (int i = 0; i < 16; i++) tot += red[i][t];
        float g = 1.f / (1.f + __expf(-tot));
        gates[((size_t)(b * 16 + t)) * 2048 + n] = g;
    }
}

// ---------------- GEMM: C = A[M][K] * Bt[N][K]^T, bf16 in, fp32 acc ----------------

template <int EPI>
__global__ __launch_bounds__(256, 2)
void gemm_bt_kernel(const unsigned short* __restrict__ A,
                    const unsigned short* __restrict__ Bt,
                    int M, int N, int K,
                    unsigned short* __restrict__ outQ,
                    unsigned short* __restrict__ outK,
                    unsigned short* __restrict__ outV,
                    float* __restrict__ outF) {
    __shared__ unsigned short As[128 * 32];
    __shared__ unsigned short Bs[128 * 32];
    const int lane = threadIdx.x & 63;
    const int w = threadIdx.x >> 6;
    const int wr = w >> 1, wc = w & 1;
    const int tm = blockIdx.y * 128;
    const int tn = blockIdx.x * 128;

    f32x4 acc[4][4];
#pragma unroll
    for (int m = 0; m < 4; m++)
#pragma unroll
        for (int n = 0; n < 4; n++) acc[m][n] = (f32x4){0.f, 0.f, 0.f, 0.f};

    const int sRow = lane >> 2;
    const int sCol = (lane & 3) * 8;

    const unsigned short* aFragBase = As + (wr * 64 + (lane & 15)) * 32 + (lane >> 4) * 8;
    const unsigned short* bFragBase = Bs + (wc * 64 + (lane & 15)) * 32 + (lane >> 4) * 8;

    for (int k0 = 0; k0 < K; k0 += 32) {
#pragma unroll
        for (int i = 0; i < 2; i++) {
            int chunk = w * 2 + i;
            int r = chunk * 16 + sRow;
            gload_lds16(A + (size_t)(tm + r) * K + k0 + sCol, (void*)(As + chunk * 512));
            gload_lds16(Bt + (size_t)(tn + r) * K + k0 + sCol, (void*)(Bs + chunk * 512));
        }
        __syncthreads();
        bf16x8 af[4], bg[4];
#pragma unroll
        for (int m = 0; m < 4; m++) af[m] = *(const bf16x8*)(aFragBase + m * 16 * 32);
#pragma unroll
        for (int n = 0; n < 4; n++) bg[n] = *(const bf16x8*)(bFragBase + n * 16 * 32);
#pragma unroll
        for (int m = 0; m < 4; m++)
#pragma unroll
            for (int n = 0; n < 4; n++)
                acc[m][n] = __builtin_amdgcn_mfma_f32_16x16x32_bf16(af[m], bg[n], acc[m][n], 0, 0, 0);
        __syncthreads();
    }

#pragma unroll
    for (int m = 0; m < 4; m++) {
        int row = tm + wr * 64 + m * 16 + (lane >> 4) * 4;
#pragma unroll
        for (int n = 0; n < 4; n++) {
            int col = tn + wc * 64 + n * 16 + (lane & 15);
#pragma unroll
            for (int r = 0; r < 4; r++) {
                float val = acc[m][n][r];
                int rr = row + r;
                if (EPI == 0) {
                    int which = col >> 10;
                    int h = (col >> 6) & 15;
                    int d = col & 63;
                    int b = rr >> 11;
                    int nn = rr & 2047;
                    size_t off = (((size_t)(b * 16 + h)) * 2048 + nn) * 64 + d;
                    if (which == 0)      outQ[off] = f2b(val * 0.125f);
                    else if (which == 1) outK[off] = f2b(val);
                    else                 outV[off] = f2b(val);
                } else {
                    outF[(size_t)rr * N + col] = val;
                }
            }
        }
    }
}

// ---------------- flash attention: softcap + causal + gate ----------------
// Swapped-operand S^T = mfma(K, Q): lane owns one q-row (q = lane&15).
// KEY: tanh softcap bounds |s| <= 50, so NO running max is needed:
// p = exp(s) directly (fp32/bf16 safe: e^50=5e21, sums<=1e25 << 3.4e38).
// => no max reduce, no alpha, no O rescale, no cross-lane ops in the loop.
// Per-lane partial l-sum; single cross-lane reduce at epilogue.
// P stays in registers (cvt_pk), V pre-permuted so PV A-operand = 16B loads.
// No LDS, no barriers. 512 blocks = 32 bh x 16 pairs (q-tiles {p, 31-p}).

__global__ __launch_bounds__(256)
void attn_kernel(const unsigned short* __restrict__ Q,
                 const unsigned short* __restrict__ Kg,
                 const unsigned short* __restrict__ Vp,
                 const float* __restrict__ Gates,
                 unsigned short* __restrict__ Out) {
    const int lane = threadIdx.x & 63;
    const int w = threadIdx.x >> 6;
    const int g = lane >> 4;        // lane-group 0..3
    const int ql = lane & 15;       // q (and d) sub-index

    // XCD-chunked bijective swizzle: XCD i gets blocks [64i, 64i+64) = 4 heads
    const int wgid = (blockIdx.x & 7) * 64 + (blockIdx.x >> 3);
    const int bh = wgid >> 4;
    const int pair = wgid & 15;
    const int b = bh >> 4;
    const int h = bh & 15;

    const size_t headBase = (size_t)bh * 2048 * 64;
    const float LOG2E = 1.4426950408889634f;

    // K fragment base (A-operand of QK^T): row k=ql, d-slots 8g..8g+7
    const unsigned short* Kfr = Kg + headBase + (size_t)ql * 64 + g * 8;
    // Vp fragment base (A-operand of PV): d-row ql (+16*nblk), slot base g*16
    const unsigned short* Vfr = Vp + (size_t)bh * 131072 + (size_t)ql * 2048 + g * 16;

    bf16x8 kb[4][2];
#pragma unroll
    for (int n = 0; n < 4; n++) {
        const unsigned short* kp = Kfr + (size_t)(n * 16) * 64;
        kb[n][0] = *(const bf16x8*)kp;
        kb[n][1] = *(const bf16x8*)(kp + 32);
    }

    for (int half = 0; half < 2; half++) {
        const int qt = half ? (31 - pair) : pair;
        const int qglob = qt * 64 + w * 16 + ql;

        const unsigned short* qp = Q + headBase + (size_t)qglob * 64 + g * 8;
        bf16x8 qa0 = *(const bf16x8*)qp;
        bf16x8 qa1 = *(const bf16x8*)(qp + 32);

        float lsum = 0.f;
        f32x4 o[4];
#pragma unroll
        for (int n = 0; n < 4; n++) o[n] = (f32x4){0.f, 0.f, 0.f, 0.f};

        for (int jt = 0; jt <= qt; ++jt) {
            // S^T = K Q^T : lane holds S[k = jt*64+16n+4g+r][q = qglob]
            f32x4 s[4];
#pragma unroll
            for (int n = 0; n < 4; n++) {
                f32x4 sv = (f32x4){0.f, 0.f, 0.f, 0.f};
                sv = __builtin_amdgcn_mfma_f32_16x16x32_bf16(kb[n][0], qa0, sv, 0, 0, 0);
                sv = __builtin_amdgcn_mfma_f32_16x16x32_bf16(kb[n][1], qa1, sv, 0, 0, 0);
                s[n] = sv;
            }

            // prefetch next K tile (jt==qt loads tile 0 for the next half)
            {
                int jn = (jt < qt) ? jt + 1 : 0;
#pragma unroll
                for (int n = 0; n < 4; n++) {
                    const unsigned short* kp = Kfr + (size_t)(jn * 64 + n * 16) * 64;
                    kb[n][0] = *(const bf16x8*)kp;
                    kb[n][1] = *(const bf16x8*)(kp + 32);
                }
            }

            // V loads for this tile (pre-permuted layout -> plain 16B loads)
            bf16x8 vA[4], vB[4];
            {
                const unsigned short* vbase = Vfr + jt * 64;
#pragma unroll
                for (int n = 0; n < 4; n++) {
                    const unsigned short* vp = vbase + (size_t)(n * 16) * 2048;
                    vA[n] = *(const bf16x8*)vp;
                    vB[n] = *(const bf16x8*)(vp + 8);
                }
            }

            // softcap, causal mask, p = exp(s) with FIXED max (softcap bounds s)
            const bool diag = (jt == qt);
            float rs = 0.f;
#pragma unroll
            for (int n = 0; n < 4; n++) {
                int k0 = jt * 64 + n * 16 + 4 * g;
#pragma unroll
                for (int r = 0; r < 4; r++) {
                    float x = s[n][r];
                    float t = __builtin_amdgcn_exp2f(x * 0.057707801635559964f);
                    float sc = 50.f - 100.f * __builtin_amdgcn_rcpf(t + 1.f);
                    if (diag && (k0 + r) > qglob) sc = -1e30f;
                    float p = __builtin_amdgcn_exp2f(sc * LOG2E);
                    s[n][r] = p;
                    rs += p;
                }
            }
            lsum += rs;

            // P -> bf16 B-operands entirely in registers
            union PU { unsigned int u[4]; bf16x8 v; };
            PU p0, p1;
            p0.u[0] = cvtpk(s[0][0], s[0][1]);
            p0.u[1] = cvtpk(s[0][2], s[0][3]);
            p0.u[2] = cvtpk(s[1][0], s[1][1]);
            p0.u[3] = cvtpk(s[1][2], s[1][3]);
            p1.u[0] = cvtpk(s[2][0], s[2][1]);
            p1.u[1] = cvtpk(s[2][2], s[2][3]);
            p1.u[2] = cvtpk(s[3][0], s[3][1]);
            p1.u[3] = cvtpk(s[3][2], s[3][3]);

            // O^T += V^T P^T  (Vp layout matches P's k-slot permutation)
#pragma unroll
            for (int n = 0; n < 4; n++) {
                o[n] = __builtin_amdgcn_mfma_f32_16x16x32_bf16(vA[n], p0.v, o[n], 0, 0, 0);
                o[n] = __builtin_amdgcn_mfma_f32_16x16x32_bf16(vB[n], p1.v, o[n], 0, 0, 0);
            }
        }

        // epilogue: cross-lane l reduce (once), /l, *gate, pack 4 d per store
        float l = lsum;
        l += __shfl_xor(l, 16);
        l += __shfl_xor(l, 32);
        float gate = Gates[(size_t)bh * 2048 + qglob];
        float inv = gate / l;
        unsigned short* orow = Out + ((size_t)(b * 2048) + qglob) * 1024 + h * 64;
#pragma unroll
        for (int n = 0; n < 4; n++) {
            ushort4 st;
            st.x = f2b(o[n][0] * inv);
            st.y = f2b(o[n][1] * inv);
            st.z = f2b(o[n][2] * inv);
            st.w = f2b(o[n][3] * inv);
            *(ushort4*)(orow + n * 16 + 4 * g) = st;
        }
    }
}

// ---------------- launch ----------------

extern "C" void kernel_launch(void* const* d_in, const int* in_sizes, int n_in,
                              void* d_out, int out_size, void* d_ws, size_t ws_size,
                              hipStream_t stream) {
    const float* x       = (const float*)d_in[0];   // [2][2048][1024]
    const float* w_qkv   = (const float*)d_in[1];   // [1024][3072]
    const float* w_gates = (const float*)d_in[2];   // [1024][16]
    const float* w_out   = (const float*)d_in[3];   // [1024][1024]
    float* out = (float*)d_out;                     // [2][2048][1024]

    char* ws = (char*)d_ws;
    unsigned short* x_bf  = (unsigned short*)(ws);                      // 8 MB (reused as Vp later)
    unsigned short* wqkvT = (unsigned short*)(ws + ((size_t)8  << 20)); // 6 MB
    unsigned short* woutT = (unsigned short*)(ws + ((size_t)14 << 20)); // 2 MB
    unsigned short* qB    = (unsigned short*)(ws + ((size_t)16 << 20)); // 8 MB
    unsigned short* kB    = (unsigned short*)(ws + ((size_t)24 << 20)); // 8 MB
    unsigned short* vB    = (unsigned short*)(ws + ((size_t)32 << 20)); // 8 MB
    float*          gates = (float*)(ws + ((size_t)40 << 20));          // 256 KB
    unsigned short* attnO = (unsigned short*)(ws + ((size_t)41 << 20)); // 8 MB
    unsigned short* vP    = x_bf;                                       // reuse after gemm0

    cvt_x_kernel<<<dim3(4096), dim3(256), 0, stream>>>(x, x_bf);
    transpose_cvt<<<dim3(3072 / 32, 1024 / 32), dim3(32, 8), 0, stream>>>(w_qkv, wqkvT, 1024, 3072);
    transpose_cvt<<<dim3(1024 / 32, 1024 / 32), dim3(32, 8), 0, stream>>>(w_out, woutT, 1024, 1024);
    gates_kernel<<<dim3(4096), dim3(256), 0, stream>>>(x, w_gates, gates);

    gemm_bt_kernel<0><<<dim3(3072 / 128, 4096 / 128), dim3(256), 0, stream>>>(
        x_bf, wqkvT, 4096, 3072, 1024, qB, kB, vB, (float*)nullptr);

    vtrans_kernel<<<dim3(32, 32), dim3(256), 0, stream>>>(vB, vP);

    attn_kernel<<<dim3(512), dim3(256), 0, stream>>>(qB, kB, vP, gates, attnO);

    gemm_bt_kernel<1><<<dim3(1024 / 128, 4096 / 128), dim3(256), 0, stream>>>(
        attnO, woutT, 4096, 1024, 1024, nullptr, nullptr, nullptr, out);
}